// Round 16
// baseline (657.938 us; speedup 1.0000x reference)
//
#include <hip/hip_runtime.h>

#define T_STEPS 1024
#define B_TOT   512
#define VOCAB   1000
#define EMB     64
#define HID     64
#define GATES   256   // 4*HID

typedef float f4 __attribute__((ext_vector_type(4)));
typedef float f2 __attribute__((ext_vector_type(2)));

__device__ __forceinline__ float fast_rcp(float x)  { return __builtin_amdgcn_rcpf(x); }
__device__ __forceinline__ float fast_exp2(float x) { return __builtin_amdgcn_exp2f(x); }

__device__ __forceinline__ float sigmoid_f(float x) {
    return fast_rcp(1.0f + fast_exp2(-1.4426950408889634f * x));
}
__device__ __forceinline__ float tanh_f(float x) {
    float e = fast_exp2(2.8853900817779268f * x);
    return 1.0f - 2.0f * fast_rcp(e + 1.0f);
}

// packed fp32 FMA: 2 MACs/instr at full VALU issue rate (measured R14).
__device__ __forceinline__ void pk_fma_acc(f2& acc, f2 a, f2 b) {
    asm("v_pk_fma_f32 %0, %1, %2, %0" : "+v"(acc) : "v"(a), "v"(b));
}

// ---------------------------------------------------------------------------
// Kernel 1: zx table. Layout [dir][vocab][wave][unit][pair]:
//   thread j (0..255): p=j&1, u=(j>>1)&63, w=j>>7, source col=(2w+p)*64+u.
// Recurrent lane (w,u) gathers float2 index tok*128 + w*64 + u.
// ---------------------------------------------------------------------------
__global__ __launch_bounds__(256, 4)
void zx_table_kernel(const float* __restrict__ emb,
                     const float* __restrict__ Wx_f, const float* __restrict__ b_f,
                     const float* __restrict__ Wx_b, const float* __restrict__ b_b,
                     float* __restrict__ zx_tab)
{
    const int bid = blockIdx.x;            // 0..1999
    const int dir = bid / VOCAB;
    const int v   = bid - dir * VOCAB;
    const int j   = threadIdx.x;
    const int p   = j & 1;
    const int u   = (j >> 1) & 63;
    const int w   = j >> 7;
    const int col = (2 * w + p) * HID + u;

    const float* __restrict__ Wx = dir ? Wx_b : Wx_f;
    const float* __restrict__ bv = dir ? b_b  : b_f;

    __shared__ float4 x4[EMB / 4];
    if (j < EMB / 4) x4[j] = ((const float4*)emb)[v * (EMB / 4) + j];
    __syncthreads();

    float a0 = bv[col], a1 = 0.f, a2 = 0.f, a3 = 0.f;
#pragma unroll
    for (int q = 0; q < EMB / 4; ++q) {
        float4 xv = x4[q];
        a0 = fmaf(xv.x, Wx[(4 * q + 0) * GATES + col], a0);
        a1 = fmaf(xv.y, Wx[(4 * q + 1) * GATES + col], a1);
        a2 = fmaf(xv.z, Wx[(4 * q + 2) * GATES + col], a2);
        a3 = fmaf(xv.w, Wx[(4 * q + 3) * GATES + col], a3);
    }
    zx_tab[(dir * VOCAB + v) * GATES + j] = (a0 + a1) + (a2 + a3);
}

// ---------------------------------------------------------------------------
// Kernel 2: recurrence — R14 (pk_fma dot) with ONE barrier per step.
// Block = 128 thr = 2 waves per (dir,row): 1024 blocks -> 2 waves/SIMD.
//   wave 0, lane u: gates i,f of unit u ; wave 1, lane u: gates g,o.
// Changes vs R14 (single variable: remove the 2nd barrier + act round-trip
// from the critical path):
//   * per-wave h copies hb[w][64]: h write -> next-step read is SAME-WAVE
//     lgkmcnt ordering, needs no barrier.
//   * waves exchange only their own-gate acts (f2, parity buffers); after
//     the single barrier BOTH waves redundantly compute the identical c/h
//     update (bit-identical inputs -> the two h copies stay bit-identical).
// ---------------------------------------------------------------------------
__global__ __launch_bounds__(128, 2)
void lstm_rec_kernel(const int* __restrict__ tokens,
                     const float* __restrict__ Wh_f,
                     const float* __restrict__ Wh_b,
                     const float* __restrict__ zx_tab,
                     float* __restrict__ out)
{
    const int bx  = blockIdx.x;        // 0..1023
    const int dir = bx >> 9;
    const int row = bx & 511;
    const int u   = threadIdx.x & 63;  // hidden unit
    const int w   = threadIdx.x >> 6;  // wave id: 0 -> gates i,f ; 1 -> g,o

    const float* __restrict__ Wh   = dir ? Wh_b : Wh_f;
    const f2*    __restrict__ zx2  = (const f2*)(zx_tab + dir * (VOCAB * GATES));
    const int*   __restrict__ trow = tokens + row * T_STEPS;

    // 128 register-resident fp32 weights as 64 packed f2 pairs.
    const int colA = (2 * w) * HID + u;
    const int colB = colA + HID;
    f2 whA2[HID / 2], whB2[HID / 2];
#pragma unroll
    for (int m = 0; m < HID / 2; ++m) {
        f2 a; a.x = Wh[(2 * m) * GATES + colA]; a.y = Wh[(2 * m + 1) * GATES + colA];
        whA2[m] = a;
        f2 b; b.x = Wh[(2 * m) * GATES + colB]; b.y = Wh[(2 * m + 1) * GATES + colB];
        whB2[m] = b;
    }

    __shared__ float hb[2][HID];       // PER-WAVE h copy (bit-identical pair)
    __shared__ f2    acx[2][2][HID];   // [parity][wave][unit] own-gate acts

    if (threadIdx.x < HID) hb[0][threadIdx.x] = 0.0f;
    else                   hb[1][threadIdx.x - HID] = 0.0f;
    float c = 0.0f, hval = 0.0f;
    int   par = 0;
    __syncthreads();

    // wave-uniform token chain + zx prefetch (float2 per lane)
    int tokc = trow[dir ? (T_STEPS - 1) : 0];
    int tokn = trow[dir ? (T_STEPS - 2) : 1];
    f2  zxc  = zx2[tokc * 128 + w * 64 + u];

    const f4* __restrict__ hb4 = (const f4*)&hb[w][0];   // own copy only

#pragma unroll 1
    for (int t = 0; t < T_STEPS; ++t) {
        // prefetches first: latency hides under the pk_fma block
        int t2   = (t + 2 < T_STEPS) ? (t + 2) : (T_STEPS - 1);
        int tokf = trow[dir ? (T_STEPS - 1 - t2) : t2];
        f2  zxn  = zx2[tokn * 128 + w * 64 + u];

        // ---- two 64-dim dots as 64 pk_fma (4 packed chains), own h copy ----
        f2 accA0; accA0.x = zxc.x; accA0.y = 0.f;
        f2 accA1; accA1.x = 0.f;   accA1.y = 0.f;
        f2 accB0; accB0.x = zxc.y; accB0.y = 0.f;
        f2 accB1; accB1.x = 0.f;   accB1.y = 0.f;
#pragma unroll
        for (int q = 0; q < HID / 4; ++q) {
            f4 hv = hb4[q];                      // LDS broadcast, conflict-free
            f2 hlo; hlo.x = hv.x; hlo.y = hv.y;
            f2 hhi; hhi.x = hv.z; hhi.y = hv.w;
            pk_fma_acc(accA0, hlo, whA2[2 * q]);
            pk_fma_acc(accA1, hhi, whA2[2 * q + 1]);
            pk_fma_acc(accB0, hlo, whB2[2 * q]);
            pk_fma_acc(accB1, hhi, whB2[2 * q + 1]);
        }
        float zA = (accA0.x + accA1.x) + (accA0.y + accA1.y);
        float zB = (accB0.x + accB1.x) + (accB0.y + accB1.y);

        // ---- own-gate activations, publish (parity slot) ----
        float actA = (w == 0) ? sigmoid_f(zA) : tanh_f(zA);   // i : g
        float actB = sigmoid_f(zB);                           // f : o
        f2 mine; mine.x = actA; mine.y = actB;
        acx[par][w][u] = mine;
        __syncthreads();                 // the ONLY barrier per step

        // ---- redundant update on BOTH waves (bit-identical) ----
        f2 other = acx[par][w ^ 1][u];
        float ig = (w == 0) ? actA    : other.x;
        float fg = (w == 0) ? actB    : other.y;
        float gg = (w == 0) ? other.x : actA;
        float og = (w == 0) ? other.y : actB;
        if (tokc != 0) {                 // Keras mask_zero: carry when padded
            c    = fmaf(fg, c, ig * gg);
            hval = og * tanh_f(c);
            hb[w][u] = hval;             // own copy; same-wave ordering only
        }
        par ^= 1;

        tokc = tokn; tokn = tokf; zxc = zxn;
    }

    if (w == 0)
        out[row * (2 * HID) + dir * HID + u] = hval;
}

extern "C" void kernel_launch(void* const* d_in, const int* in_sizes, int n_in,
                              void* d_out, int out_size, void* d_ws, size_t ws_size,
                              hipStream_t stream) {
    const int*   tokens = (const int*)  d_in[0];
    const float* emb    = (const float*)d_in[1];
    const float* Wx_f   = (const float*)d_in[2];
    const float* Wh_f   = (const float*)d_in[3];
    const float* b_f    = (const float*)d_in[4];
    const float* Wx_b   = (const float*)d_in[5];
    const float* Wh_b   = (const float*)d_in[6];
    const float* b_b    = (const float*)d_in[7];
    float* out = (float*)d_out;

    float* zx_tab = (float*)d_ws;   // 2*1000*256*4 = 1.95 MB of d_ws

    hipLaunchKernelGGL(zx_table_kernel, dim3(2 * VOCAB), dim3(GATES), 0, stream,
                       emb, Wx_f, b_f, Wx_b, b_b, zx_tab);
    hipLaunchKernelGGL(lstm_rec_kernel, dim3(2 * B_TOT), dim3(128), 0, stream,
                       tokens, Wh_f, Wh_b, zx_tab, out);
}

// Round 17
// 575.158 us; speedup vs baseline: 1.1439x; 1.1439x over previous
//
#include <hip/hip_runtime.h>

#define T_STEPS 1024
#define B_TOT   512
#define VOCAB   1000
#define EMB     64
#define HID     64
#define GATES   256   // 4*HID

typedef float f4 __attribute__((ext_vector_type(4)));
typedef float f2 __attribute__((ext_vector_type(2)));

__device__ __forceinline__ float fast_rcp(float x)  { return __builtin_amdgcn_rcpf(x); }
__device__ __forceinline__ float fast_exp2(float x) { return __builtin_amdgcn_exp2f(x); }

__device__ __forceinline__ float sigmoid_f(float x) {
    return fast_rcp(1.0f + fast_exp2(-1.4426950408889634f * x));
}
__device__ __forceinline__ float tanh_f(float x) {
    float e = fast_exp2(2.8853900817779268f * x);
    return 1.0f - 2.0f * fast_rcp(e + 1.0f);
}

// packed fp32 FMA: 2 MACs/instr at full VALU issue rate (measured R14:
// VALUBusy 85->55% replacing 128 scalar fmaf with 64 pk_fma).
__device__ __forceinline__ void pk_fma_acc(f2& acc, f2 a, f2 b) {
    asm("v_pk_fma_f32 %0, %1, %2, %0" : "+v"(acc) : "v"(a), "v"(b));
}

// ---------------------------------------------------------------------------
// Kernel 1: zx table. Layout [dir][vocab][wave][unit][pair]:
//   thread j (0..255): p=j&1, u=(j>>1)&63, w=j>>7, source col=(2w+p)*64+u.
// Recurrent lane (w,u) gathers float2 index tok*128 + w*64 + u.
// ---------------------------------------------------------------------------
__global__ __launch_bounds__(256, 4)
void zx_table_kernel(const float* __restrict__ emb,
                     const float* __restrict__ Wx_f, const float* __restrict__ b_f,
                     const float* __restrict__ Wx_b, const float* __restrict__ b_b,
                     float* __restrict__ zx_tab)
{
    const int bid = blockIdx.x;            // 0..1999
    const int dir = bid / VOCAB;
    const int v   = bid - dir * VOCAB;
    const int j   = threadIdx.x;
    const int p   = j & 1;
    const int u   = (j >> 1) & 63;
    const int w   = j >> 7;
    const int col = (2 * w + p) * HID + u;

    const float* __restrict__ Wx = dir ? Wx_b : Wx_f;
    const float* __restrict__ bv = dir ? b_b  : b_f;

    __shared__ float4 x4[EMB / 4];
    if (j < EMB / 4) x4[j] = ((const float4*)emb)[v * (EMB / 4) + j];
    __syncthreads();

    float a0 = bv[col], a1 = 0.f, a2 = 0.f, a3 = 0.f;
#pragma unroll
    for (int q = 0; q < EMB / 4; ++q) {
        float4 xv = x4[q];
        a0 = fmaf(xv.x, Wx[(4 * q + 0) * GATES + col], a0);
        a1 = fmaf(xv.y, Wx[(4 * q + 1) * GATES + col], a1);
        a2 = fmaf(xv.z, Wx[(4 * q + 2) * GATES + col], a2);
        a3 = fmaf(xv.w, Wx[(4 * q + 3) * GATES + col], a3);
    }
    zx_tab[(dir * VOCAB + v) * GATES + j] = (a0 + a1) + (a2 + a3);
}

// ---------------------------------------------------------------------------
// Kernel 2: recurrence — R14 winner (pk_fma, 2 waves, 2 barriers) + 3 trims:
//   (1) s_setprio(1) around the dot: cross-block wave arbitration — prefer
//       the compute-phase wave over the exchange-phase wave on each SIMD.
//   (2) branchless masked update (cndmask select; bit-identical).
//   (3) unroll 2: loop bookkeeping amortized, prefetches cross-scheduled.
// Block = 128 thr = 2 waves per (dir,row): 1024 blocks -> 2 waves/SIMD.
//   wave 0, lane u: gates i,f of unit u ; wave 1, lane u: gates g,o.
// ---------------------------------------------------------------------------
__global__ __launch_bounds__(128, 2)
void lstm_rec_kernel(const int* __restrict__ tokens,
                     const float* __restrict__ Wh_f,
                     const float* __restrict__ Wh_b,
                     const float* __restrict__ zx_tab,
                     float* __restrict__ out)
{
    const int bx  = blockIdx.x;        // 0..1023
    const int dir = bx >> 9;
    const int row = bx & 511;
    const int u   = threadIdx.x & 63;  // hidden unit
    const int w   = threadIdx.x >> 6;  // wave id: 0 -> gates i,f ; 1 -> g,o

    const float* __restrict__ Wh   = dir ? Wh_b : Wh_f;
    const f2*    __restrict__ zx2  = (const f2*)(zx_tab + dir * (VOCAB * GATES));
    const int*   __restrict__ trow = tokens + row * T_STEPS;

    // 128 register-resident fp32 weights as 64 packed f2 pairs.
    const int colA = (2 * w) * HID + u;
    const int colB = colA + HID;
    f2 whA2[HID / 2], whB2[HID / 2];
#pragma unroll
    for (int m = 0; m < HID / 2; ++m) {
        f2 a; a.x = Wh[(2 * m) * GATES + colA]; a.y = Wh[(2 * m + 1) * GATES + colA];
        whA2[m] = a;
        f2 b; b.x = Wh[(2 * m) * GATES + colB]; b.y = Wh[(2 * m + 1) * GATES + colB];
        whB2[m] = b;
    }

    __shared__ float hbuf[HID];        // h broadcast (fp32)
    __shared__ f2    act2[HID];        // wave1 -> wave0: {g, o}

    if (threadIdx.x < HID) hbuf[threadIdx.x] = 0.0f;
    float c = 0.0f;                    // cell state (wave 0 lanes)
    __syncthreads();

    // wave-uniform token chain + zx prefetch (float2 per lane)
    int tokc = trow[dir ? (T_STEPS - 1) : 0];
    int tokn = trow[dir ? (T_STEPS - 2) : 1];
    f2  zxc  = zx2[tokc * 128 + w * 64 + u];

    const f4* __restrict__ hb4 = (const f4*)hbuf;

#pragma unroll 2
    for (int t = 0; t < T_STEPS; ++t) {
        // prefetches first: latency hides under the pk_fma block
        int t2   = (t + 2 < T_STEPS) ? (t + 2) : (T_STEPS - 1);
        int tokf = trow[dir ? (T_STEPS - 1 - t2) : t2];
        f2  zxn  = zx2[tokn * 128 + w * 64 + u];

        // ---- two 64-dim dots as 64 pk_fma (4 packed chains) ----
        __builtin_amdgcn_s_setprio(1);
        f2 accA0; accA0.x = zxc.x; accA0.y = 0.f;
        f2 accA1; accA1.x = 0.f;   accA1.y = 0.f;
        f2 accB0; accB0.x = zxc.y; accB0.y = 0.f;
        f2 accB1; accB1.x = 0.f;   accB1.y = 0.f;
#pragma unroll
        for (int q = 0; q < HID / 4; ++q) {
            f4 hv = hb4[q];                      // LDS broadcast, conflict-free
            f2 hlo; hlo.x = hv.x; hlo.y = hv.y;
            f2 hhi; hhi.x = hv.z; hhi.y = hv.w;
            pk_fma_acc(accA0, hlo, whA2[2 * q]);
            pk_fma_acc(accA1, hhi, whA2[2 * q + 1]);
            pk_fma_acc(accB0, hlo, whB2[2 * q]);
            pk_fma_acc(accB1, hhi, whB2[2 * q + 1]);
        }
        __builtin_amdgcn_s_setprio(0);
        float zA = (accA0.x + accA1.x) + (accA0.y + accA1.y);
        float zB = (accB0.x + accB1.x) + (accB0.y + accB1.y);

        // ---- own-gate activations (both waves busy, wave-uniform branch) ----
        float actA, actB;
        if (w == 0) {                  // i, f
            actA = sigmoid_f(zA);
            actB = sigmoid_f(zB);
        } else {                       // g, o
            actA = tanh_f(zA);
            actB = sigmoid_f(zB);
            f2 go; go.x = actA; go.y = actB;
            act2[u] = go;
        }
        __syncthreads();

        // ---- state update: wave 0, lane-parallel, branchless mask ----
        if (w == 0) {
            f2 go = act2[u];
            float c_new = fmaf(actB, c, actA * go.x);   // f*c + i*g
            float h_new = go.y * tanh_f(c_new);         // o*tanh(c)
            bool m = (tokc != 0);                       // Keras mask_zero
            c = m ? c_new : c;
            hbuf[u] = m ? h_new : hbuf[u];
        }
        __syncthreads();

        tokc = tokn; tokn = tokf; zxc = zxn;
    }

    if (w == 0)
        out[row * (2 * HID) + dir * HID + u] = hbuf[u];
}

extern "C" void kernel_launch(void* const* d_in, const int* in_sizes, int n_in,
                              void* d_out, int out_size, void* d_ws, size_t ws_size,
                              hipStream_t stream) {
    const int*   tokens = (const int*)  d_in[0];
    const float* emb    = (const float*)d_in[1];
    const float* Wx_f   = (const float*)d_in[2];
    const float* Wh_f   = (const float*)d_in[3];
    const float* b_f    = (const float*)d_in[4];
    const float* Wx_b   = (const float*)d_in[5];
    const float* Wh_b   = (const float*)d_in[6];
    const float* b_b    = (const float*)d_in[7];
    float* out = (float*)d_out;

    float* zx_tab = (float*)d_ws;   // 2*1000*256*4 = 1.95 MB of d_ws

    hipLaunchKernelGGL(zx_table_kernel, dim3(2 * VOCAB), dim3(GATES), 0, stream,
                       emb, Wx_f, b_f, Wx_b, b_b, zx_tab);
    hipLaunchKernelGGL(lstm_rec_kernel, dim3(2 * B_TOT), dim3(128), 0, stream,
                       tokens, Wh_f, Wh_b, zx_tab, out);
}